// Round 1
// baseline (618.909 us; speedup 1.0000x reference)
//
#include <hip/hip_runtime.h>
#include <math.h>

#define NSTEP 730
#define NGRID 1500
#define LENF  15
#define PRECS 1e-5f

// One thread per (grid, mu) chain. lane = (g_local<<4) | mu, 4 grids per
// 64-thread block, 375 blocks (1500/4 exactly).
__global__ __launch_bounds__(64)
void hbv_scan_kernel(const float* __restrict__ x,       // (730,1500,3)
                     const float* __restrict__ params,  // (1500,12,16)
                     const float* __restrict__ rtwts,   // (1500,2)
                     float* __restrict__ out)           // (730,1500,5)
{
    const int lane = threadIdx.x;
    const int g = blockIdx.x * 4 + (lane >> 4);
    const int m = lane & 15;

    // ---- scaled parameters (PARA_SCALE) ----
    const float lo[12] = {1.f, 50.f, 0.05f, 0.01f, 0.001f, 0.2f, 0.f, 0.f, -2.5f, 0.5f, 0.f, 0.f};
    const float hi[12] = {6.f, 1000.f, 0.9f, 0.5f, 0.2f, 1.f, 10.f, 100.f, 2.5f, 10.f, 0.1f, 0.2f};
    float p[12];
    #pragma unroll
    for (int i = 0; i < 12; ++i)
        p[i] = lo[i] + params[(g*12 + i)*16 + m] * (hi[i] - lo[i]);
    const float pBETA=p[0], pFC=p[1], pK0=p[2], pK1=p[3], pK2=p[4], pLP=p[5],
                pPERC=p[6], pUZL=p[7], pTT=p[8], pCFMAX=p[9], pCFR=p[10], pCWH=p[11];

    // ---- routing weights (depend on grid only; identical on all 16 mu lanes) ----
    const float ta = rtwts[g*2+0] * 2.9f;               // ROUT_SCALE[0] = [0,2.9]
    const float tb = rtwts[g*2+1] * 6.5f;               // ROUT_SCALE[1] = [0,6.5]
    const float aa = fmaxf(ta, 0.f) + 0.1f;
    const float th = fmaxf(tb, 0.f) + 0.5f;
    float w[LENF];
    const float c0 = expf(-lgammaf(aa)) * powf(th, -aa);
    float wsum = 0.f;
    #pragma unroll
    for (int k = 0; k < LENF; ++k) {
        const float tt = (float)k + 0.5f;
        w[k] = c0 * powf(tt, aa - 1.f) * expf(-tt / th);
        wsum += w[k];
    }
    const float winv = 1.f / wsum;
    #pragma unroll
    for (int k = 0; k < LENF; ++k) w[k] *= winv;

    // rolling history of grid-mean Qsim for the fused routing convolution
    float h[LENF-1];
    #pragma unroll
    for (int k = 0; k < LENF-1; ++k) h[k] = 0.f;

    float SNOWPACK=0.001f, MELTWATER=0.001f, SM=0.001f, SUZ=0.001f, SLZ=0.001f;
    const float inv16 = 1.f/16.f;

    for (int t = 0; t < NSTEP; ++t) {
        const int xb = (t*NGRID + g)*3;
        const float Pm = x[xb+0];
        const float Tm = x[xb+1];
        const float Em = x[xb+2];

        const float is_rain = (Tm >= pTT) ? 1.f : 0.f;
        const float RAIN = Pm * is_rain;
        const float SNOW = Pm * (1.f - is_rain);
        SNOWPACK += SNOW;
        const float melt = fminf(fmaxf(pCFMAX*(Tm - pTT), 0.f), SNOWPACK);
        MELTWATER += melt;
        SNOWPACK -= melt;
        const float refreeze = fminf(fmaxf(pCFR*pCFMAX*(pTT - Tm), 0.f), MELTWATER);
        SNOWPACK += refreeze;
        MELTWATER -= refreeze;
        const float tosoil = fmaxf(MELTWATER - pCWH*SNOWPACK, 0.f);
        MELTWATER -= tosoil;
        float sw = __powf(SM / pFC, pBETA);
        sw = fminf(fmaxf(sw, 0.f), 1.f);
        const float recharge = (RAIN + tosoil) * sw;
        SM = SM + RAIN + tosoil - recharge;
        const float excess = fmaxf(SM - pFC, 0.f);
        SM -= excess;
        const float evap = fminf(fmaxf(SM / (pLP*pFC), 0.f), 1.f);
        const float ETact = fminf(SM, Em * evap);
        SM = fmaxf(SM - ETact, PRECS);
        SUZ += recharge + excess;
        const float PERC = fminf(SUZ, pPERC);
        SUZ -= PERC;
        const float Q0 = pK0 * fmaxf(SUZ - pUZL, 0.f);
        SUZ -= Q0;
        const float Q1 = pK1 * SUZ;
        SUZ -= Q1;
        SLZ += PERC;
        const float Q2 = pK2 * SLZ;
        SLZ -= Q2;

        // ---- mean over the 16 mu lanes (butterfly: result on all lanes) ----
        float rq = Q0 + Q1 + Q2;
        float r0 = Q0, r1 = Q1, r2 = Q2, re = ETact;
        #pragma unroll
        for (int mask = 1; mask < 16; mask <<= 1) {
            rq += __shfl_xor(rq, mask);
            r0 += __shfl_xor(r0, mask);
            r1 += __shfl_xor(r1, mask);
            r2 += __shfl_xor(r2, mask);
            re += __shfl_xor(re, mask);
        }
        rq *= inv16;

        // ---- fused 15-tap routing convolution (all indices compile-time) ----
        float Qs = w[0] * rq;
        #pragma unroll
        for (int k = 1; k < LENF; ++k) Qs += w[k] * h[k-1];
        #pragma unroll
        for (int k = LENF-2; k >= 1; --k) h[k] = h[k-1];
        h[0] = rq;

        if (m == 0) {
            const int ob = (t*NGRID + g)*5;
            out[ob+0] = Qs;
            out[ob+1] = r0 * inv16;
            out[ob+2] = r1 * inv16;
            out[ob+3] = r2 * inv16;
            out[ob+4] = re * inv16;
        }
    }
}

extern "C" void kernel_launch(void* const* d_in, const int* in_sizes, int n_in,
                              void* d_out, int out_size, void* d_ws, size_t ws_size,
                              hipStream_t stream)
{
    const float* x      = (const float*)d_in[0];
    const float* params = (const float*)d_in[1];
    const float* rt     = (const float*)d_in[2];
    float* out = (float*)d_out;

    dim3 grid(NGRID / 4), block(64);
    hipLaunchKernelGGL(hbv_scan_kernel, grid, block, 0, stream, x, params, rt, out);
}

// Round 2
// 528.948 us; speedup vs baseline: 1.1701x; 1.1701x over previous
//
#include <hip/hip_runtime.h>
#include <math.h>

#define NSTEP 730
#define NGRID 1500
#define LENF  15
#define PRECS 1e-5f
#define U     5        // 730 = 146 * 5, no tail

// One thread per (grid, mu) chain. lane = (g_local<<4) | mu, 4 grids per
// 64-thread block, 375 blocks. Latency-bound: ~1 wave/SIMD, so everything
// lives in registers and latency is hidden by ILP (5-step time unroll).
__global__ __launch_bounds__(64)
void hbv_scan_kernel(const float* __restrict__ x,       // (730,1500,3)
                     const float* __restrict__ params,  // (1500,12,16)
                     const float* __restrict__ rtwts,   // (1500,2)
                     float* __restrict__ out)           // (730,1500,5)
{
    const int lane = threadIdx.x;
    const int g = blockIdx.x * 4 + (lane >> 4);
    const int m = lane & 15;

    // ---- scaled parameters (PARA_SCALE) ----
    const float lo[12] = {1.f, 50.f, 0.05f, 0.01f, 0.001f, 0.2f, 0.f, 0.f, -2.5f, 0.5f, 0.f, 0.f};
    const float hi[12] = {6.f, 1000.f, 0.9f, 0.5f, 0.2f, 1.f, 10.f, 100.f, 2.5f, 10.f, 0.1f, 0.2f};
    float p[12];
    #pragma unroll
    for (int i = 0; i < 12; ++i)
        p[i] = lo[i] + params[(g*12 + i)*16 + m] * (hi[i] - lo[i]);
    const float pBETA=p[0], pFC=p[1], pK0=p[2], pK1=p[3], pK2=p[4], pLP=p[5],
                pPERC=p[6], pUZL=p[7], pTT=p[8], pCFMAX=p[9], pCFR=p[10], pCWH=p[11];
    const float invFC   = 1.f / pFC;              // kill divides on the chain
    const float invLPFC = 1.f / (pLP * pFC);
    const float refCoef = pCFR * pCFMAX;

    // ---- routing weights (grid-only; identical on all 16 mu lanes) ----
    const float ta = rtwts[g*2+0] * 2.9f;
    const float tb = rtwts[g*2+1] * 6.5f;
    const float aa = fmaxf(ta, 0.f) + 0.1f;
    const float th = fmaxf(tb, 0.f) + 0.5f;
    float w[LENF];
    const float c0 = expf(-lgammaf(aa)) * powf(th, -aa);
    float wsum = 0.f;
    #pragma unroll
    for (int k = 0; k < LENF; ++k) {
        const float tt = (float)k + 0.5f;
        w[k] = c0 * powf(tt, aa - 1.f) * expf(-tt / th);
        wsum += w[k];
    }
    const float winv = 1.f / wsum;
    #pragma unroll
    for (int k = 0; k < LENF; ++k) w[k] *= winv;

    float h[LENF-1];
    #pragma unroll
    for (int k = 0; k < LENF-1; ++k) h[k] = 0.f;

    float SNOWPACK=0.001f, MELTWATER=0.001f, SM=0.001f, SUZ=0.001f, SLZ=0.001f;
    const float inv16 = 1.f/16.f;

    // ---- register double-buffer for x, prefetched one 5-step block ahead ----
    float Pc[U], Tc[U], Ec[U], Pn[U], Tn[U], En[U];
    #pragma unroll
    for (int u = 0; u < U; ++u) {
        const int xb = ((u)*NGRID + g)*3;
        Pc[u] = x[xb+0]; Tc[u] = x[xb+1]; Ec[u] = x[xb+2];
    }

    for (int tb = 0; tb < NSTEP; tb += U) {
        // prefetch next block (independent of everything below)
        if (tb + U < NSTEP) {
            #pragma unroll
            for (int u = 0; u < U; ++u) {
                const int xb = ((tb+U+u)*NGRID + g)*3;
                Pn[u] = x[xb+0]; Tn[u] = x[xb+1]; En[u] = x[xb+2];
            }
        }

        float q0[U], q1[U], q2[U], et[U];

        // ---- 5 sequential state updates (the only true dependence chain) ----
        #pragma unroll
        for (int u = 0; u < U; ++u) {
            const float Pm = Pc[u], Tm = Tc[u], Em = Ec[u];
            // input-only precomputables (off the state chain)
            const float is_rain = (Tm >= pTT) ? 1.f : 0.f;
            const float RAIN = Pm * is_rain;
            const float SNOW = Pm - RAIN;
            const float meltcap = fmaxf(pCFMAX*(Tm - pTT), 0.f);
            const float refcap  = fmaxf(refCoef*(pTT - Tm), 0.f);

            SNOWPACK += SNOW;
            const float melt = fminf(meltcap, SNOWPACK);
            MELTWATER += melt;
            SNOWPACK -= melt;
            const float refreeze = fminf(refcap, MELTWATER);
            SNOWPACK += refreeze;
            MELTWATER -= refreeze;
            const float tosoil = fmaxf(MELTWATER - pCWH*SNOWPACK, 0.f);
            MELTWATER -= tosoil;
            float sw = __powf(SM * invFC, pBETA);
            sw = fminf(fmaxf(sw, 0.f), 1.f);
            const float recharge = (RAIN + tosoil) * sw;
            SM = SM + RAIN + tosoil - recharge;
            const float excess = fmaxf(SM - pFC, 0.f);
            SM -= excess;
            const float evap = fminf(fmaxf(SM * invLPFC, 0.f), 1.f);
            const float ETact = fminf(SM, Em * evap);
            SM = fmaxf(SM - ETact, PRECS);
            SUZ += recharge + excess;
            const float PERC = fminf(SUZ, pPERC);
            SUZ -= PERC;
            const float Q0 = pK0 * fmaxf(SUZ - pUZL, 0.f);
            SUZ -= Q0;
            const float Q1 = pK1 * SUZ;
            SUZ -= Q1;
            SLZ += PERC;
            const float Q2 = pK2 * SLZ;
            SLZ -= Q2;

            q0[u] = Q0; q1[u] = Q1; q2[u] = Q2; et[u] = ETact;
        }

        // ---- batched reductions: 4*U = 20 independent 4-stage butterflies ----
        #pragma unroll
        for (int u = 0; u < U; ++u) {
            #pragma unroll
            for (int mask = 1; mask < 16; mask <<= 1) {
                q0[u] += __shfl_xor(q0[u], mask);
                q1[u] += __shfl_xor(q1[u], mask);
                q2[u] += __shfl_xor(q2[u], mask);
                et[u] += __shfl_xor(et[u], mask);
            }
        }

        // ---- routing convolution + output (sequential in u, off the chain) ----
        #pragma unroll
        for (int u = 0; u < U; ++u) {
            const float rq = (q0[u] + q1[u] + q2[u]) * inv16;
            float Qs = w[0] * rq;
            #pragma unroll
            for (int k = 1; k < LENF; ++k) Qs += w[k] * h[k-1];
            #pragma unroll
            for (int k = LENF-2; k >= 1; --k) h[k] = h[k-1];
            h[0] = rq;

            if (m == 0) {
                const int ob = ((tb+u)*NGRID + g)*5;
                out[ob+0] = Qs;
                out[ob+1] = q0[u] * inv16;
                out[ob+2] = q1[u] * inv16;
                out[ob+3] = q2[u] * inv16;
                out[ob+4] = et[u] * inv16;
            }
        }

        // rotate prefetch buffer
        #pragma unroll
        for (int u = 0; u < U; ++u) { Pc[u]=Pn[u]; Tc[u]=Tn[u]; Ec[u]=En[u]; }
    }
}

extern "C" void kernel_launch(void* const* d_in, const int* in_sizes, int n_in,
                              void* d_out, int out_size, void* d_ws, size_t ws_size,
                              hipStream_t stream)
{
    const float* x      = (const float*)d_in[0];
    const float* params = (const float*)d_in[1];
    const float* rt     = (const float*)d_in[2];
    float* out = (float*)d_out;

    dim3 grid(NGRID / 4), block(64);
    hipLaunchKernelGGL(hbv_scan_kernel, grid, block, 0, stream, x, params, rt, out);
}

// Round 3
// 509.936 us; speedup vs baseline: 1.2137x; 1.0373x over previous
//
#include <hip/hip_runtime.h>
#include <math.h>

#define NSTEP 730
#define NGRID 1500
#define LENF  15
#define PRECS 1e-5f
#define U     10       // 730 = 73 * 10, no tail

// One thread per (grid, mu) chain. lane = (g_local<<4) | mu, 4 grids per
// 64-thread block, 375 blocks. Latency-bound with ~1 wave/SIMD: occupancy is
// irrelevant, so __launch_bounds__(64,1) lifts the VGPR cap (no spills) and
// a 10-step time unroll provides the ILP that hides VALU/DS latency.
__global__ __launch_bounds__(64, 1)
void hbv_scan_kernel(const float* __restrict__ x,       // (730,1500,3)
                     const float* __restrict__ params,  // (1500,12,16)
                     const float* __restrict__ rtwts,   // (1500,2)
                     float* __restrict__ out)           // (730,1500,5)
{
    const int lane = threadIdx.x;
    const int g = blockIdx.x * 4 + (lane >> 4);
    const int m = lane & 15;

    // ---- scaled parameters (PARA_SCALE) ----
    const float lo[12] = {1.f, 50.f, 0.05f, 0.01f, 0.001f, 0.2f, 0.f, 0.f, -2.5f, 0.5f, 0.f, 0.f};
    const float hi[12] = {6.f, 1000.f, 0.9f, 0.5f, 0.2f, 1.f, 10.f, 100.f, 2.5f, 10.f, 0.1f, 0.2f};
    float p[12];
    #pragma unroll
    for (int i = 0; i < 12; ++i)
        p[i] = lo[i] + params[(g*12 + i)*16 + m] * (hi[i] - lo[i]);
    const float pBETA=p[0], pFC=p[1], pK0=p[2], pK1=p[3], pK2=p[4], pLP=p[5],
                pPERC=p[6], pUZL=p[7], pTT=p[8], pCFMAX=p[9], pCFR=p[10], pCWH=p[11];
    const float invFC   = 1.f / pFC;
    const float invLPFC = 1.f / (pLP * pFC);
    const float refCoef = pCFR * pCFMAX;

    // ---- routing weights (grid-only; identical on all 16 mu lanes) ----
    const float ta = rtwts[g*2+0] * 2.9f;
    const float tb = rtwts[g*2+1] * 6.5f;
    const float aa = fmaxf(ta, 0.f) + 0.1f;
    const float th = fmaxf(tb, 0.f) + 0.5f;
    float w[LENF];
    const float c0 = expf(-lgammaf(aa)) * powf(th, -aa);
    float wsum = 0.f;
    #pragma unroll
    for (int k = 0; k < LENF; ++k) {
        const float tt = (float)k + 0.5f;
        w[k] = c0 * powf(tt, aa - 1.f) * expf(-tt / th);
        wsum += w[k];
    }
    const float winv = 1.f / wsum;
    #pragma unroll
    for (int k = 0; k < LENF; ++k) w[k] *= winv;

    float h[LENF-1];
    #pragma unroll
    for (int k = 0; k < LENF-1; ++k) h[k] = 0.f;

    float SNOWPACK=0.001f, MELTWATER=0.001f, SM=0.001f, SUZ=0.001f, SLZ=0.001f;
    const float inv16 = 1.f/16.f;

    // ---- register double-buffer for x, prefetched one U-step block ahead ----
    float Pc[U], Tc[U], Ec[U], Pn[U], Tn[U], En[U];
    #pragma unroll
    for (int u = 0; u < U; ++u) {
        const int xb = (u*NGRID + g)*3;
        Pc[u] = x[xb+0]; Tc[u] = x[xb+1]; Ec[u] = x[xb+2];
    }

    for (int tb = 0; tb < NSTEP; tb += U) {
        // prefetch next block (independent of everything below)
        if (tb + U < NSTEP) {
            #pragma unroll
            for (int u = 0; u < U; ++u) {
                const int xb = ((tb+U+u)*NGRID + g)*3;
                Pn[u] = x[xb+0]; Tn[u] = x[xb+1]; En[u] = x[xb+2];
            }
        }

        float q0[U], q1[U], q2[U], et[U];

        // ---- U sequential state updates (the only true dependence chain) ----
        #pragma unroll
        for (int u = 0; u < U; ++u) {
            const float Pm = Pc[u], Tm = Tc[u], Em = Ec[u];
            const float is_rain = (Tm >= pTT) ? 1.f : 0.f;
            const float RAIN = Pm * is_rain;
            const float SNOW = Pm - RAIN;
            const float meltcap = fmaxf(pCFMAX*(Tm - pTT), 0.f);
            const float refcap  = fmaxf(refCoef*(pTT - Tm), 0.f);

            SNOWPACK += SNOW;
            const float melt = fminf(meltcap, SNOWPACK);
            MELTWATER += melt;
            SNOWPACK -= melt;
            const float refreeze = fminf(refcap, MELTWATER);
            SNOWPACK += refreeze;
            MELTWATER -= refreeze;
            const float tosoil = fmaxf(MELTWATER - pCWH*SNOWPACK, 0.f);
            MELTWATER -= tosoil;
            float sw = __powf(SM * invFC, pBETA);
            sw = fminf(fmaxf(sw, 0.f), 1.f);
            const float recharge = (RAIN + tosoil) * sw;
            SM = SM + RAIN + tosoil - recharge;
            const float excess = fmaxf(SM - pFC, 0.f);
            SM -= excess;
            const float evap = fminf(fmaxf(SM * invLPFC, 0.f), 1.f);
            const float ETact = fminf(SM, Em * evap);
            SM = fmaxf(SM - ETact, PRECS);
            SUZ += recharge + excess;
            const float PERC = fminf(SUZ, pPERC);
            SUZ -= PERC;
            const float Q0 = pK0 * fmaxf(SUZ - pUZL, 0.f);
            SUZ -= Q0;
            const float Q1 = pK1 * SUZ;
            SUZ -= Q1;
            SLZ += PERC;
            const float Q2 = pK2 * SLZ;
            SLZ -= Q2;

            q0[u] = Q0; q1[u] = Q1; q2[u] = Q2; et[u] = ETact;
        }

        // ---- batched reductions: 4*U = 40 independent 4-stage butterflies ----
        #pragma unroll
        for (int u = 0; u < U; ++u) {
            #pragma unroll
            for (int mask = 1; mask < 16; mask <<= 1) {
                q0[u] += __shfl_xor(q0[u], mask);
                q1[u] += __shfl_xor(q1[u], mask);
                q2[u] += __shfl_xor(q2[u], mask);
                et[u] += __shfl_xor(et[u], mask);
            }
        }

        // ---- batched routing convolution (all compile-time indices) ----
        float rq[U], Qs[U];
        #pragma unroll
        for (int u = 0; u < U; ++u) rq[u] = (q0[u] + q1[u] + q2[u]) * inv16;
        #pragma unroll
        for (int u = 0; u < U; ++u) {
            float acc = 0.f;
            #pragma unroll
            for (int k = 0; k < LENF; ++k)
                acc += w[k] * ((k <= u) ? rq[u-k] : h[k-1-u]);
            Qs[u] = acc;
        }
        // shift history by U (register renaming, no serial movs)
        float hn[LENF-1];
        #pragma unroll
        for (int j = 0; j < LENF-1; ++j)
            hn[j] = (j < U) ? rq[U-1-j] : h[j-U];
        #pragma unroll
        for (int j = 0; j < LENF-1; ++j) h[j] = hn[j];

        // ---- output ----
        if (m == 0) {
            #pragma unroll
            for (int u = 0; u < U; ++u) {
                const int ob = ((tb+u)*NGRID + g)*5;
                out[ob+0] = Qs[u];
                out[ob+1] = q0[u] * inv16;
                out[ob+2] = q1[u] * inv16;
                out[ob+3] = q2[u] * inv16;
                out[ob+4] = et[u] * inv16;
            }
        }

        // rotate prefetch buffer
        #pragma unroll
        for (int u = 0; u < U; ++u) { Pc[u]=Pn[u]; Tc[u]=Tn[u]; Ec[u]=En[u]; }
    }
}

extern "C" void kernel_launch(void* const* d_in, const int* in_sizes, int n_in,
                              void* d_out, int out_size, void* d_ws, size_t ws_size,
                              hipStream_t stream)
{
    const float* x      = (const float*)d_in[0];
    const float* params = (const float*)d_in[1];
    const float* rt     = (const float*)d_in[2];
    float* out = (float*)d_out;

    dim3 grid(NGRID / 4), block(64);
    hipLaunchKernelGGL(hbv_scan_kernel, grid, block, 0, stream, x, params, rt, out);
}

// Round 4
// 440.032 us; speedup vs baseline: 1.4065x; 1.1589x over previous
//
#include <hip/hip_runtime.h>
#include <math.h>

#define NSTEP  730
#define NGRID  1500
#define LENF   15
#define PRECS  1e-5f
#define CHUNK  146                 // 730 = 5 * 146
#define NCHUNK 5
#define ROWDW  12                  // dwords per time-step row (4 grids * 3 vals)
#define CHUNKDW (CHUNK*ROWDW)      // 1752
#define NLOAD  28                  // ceil(1752/64)
#define LDSPAD (CHUNKDW+16)        // slack row so s+1 read at s=145 stays in-buffer

// 16-lane (one grid's 16 mu) sum via DPP — pure VALU, no LDS/lgkmcnt.
// Butterfly: xor1 (quad_perm[1,0,3,2]), xor2 (quad_perm[2,3,0,1]),
// cross-quad (row_half_mirror), cross-half (row_mirror). Row=16 lanes on gfx9+.
template<int CTRL>
__device__ __forceinline__ float dpp_add(float v) {
    int t = __builtin_amdgcn_update_dpp(0, __float_as_int(v), CTRL, 0xF, 0xF, true);
    return v + __int_as_float(t);
}
__device__ __forceinline__ float row16_sum(float v) {
    v = dpp_add<0xB1>(v);    // quad_perm [1,0,3,2]
    v = dpp_add<0x4E>(v);    // quad_perm [2,3,0,1]
    v = dpp_add<0x141>(v);   // row_half_mirror
    v = dpp_add<0x140>(v);   // row_mirror
    return v;
}

// One thread per (grid, mu) chain; 64-thread block = 1 wave = 4 grids; 375 blocks.
// Latency-bound, 1 wave/SIMD: steady state must be VALU-only. x is staged into
// LDS in 146-step chunks (double-buffered; single-wave block -> no barriers),
// reductions are DPP, output is one coalesced 80B store per step.
__global__ __launch_bounds__(64, 1)
void hbv_scan_kernel(const float* __restrict__ x,       // (730,1500,3)
                     const float* __restrict__ params,  // (1500,12,16)
                     const float* __restrict__ rtwts,   // (1500,2)
                     float* __restrict__ out)           // (730,1500,5)
{
    __shared__ float lds[2*LDSPAD];
    const int lane = threadIdx.x;
    const int gl   = lane >> 4;              // grid-local 0..3
    const int m    = lane & 15;              // mu
    const int g    = blockIdx.x*4 + gl;
    const int G3   = blockIdx.x*12;          // dword offset of block's 48B row in x

    // ---- scaled parameters ----
    const float lo[12] = {1.f, 50.f, 0.05f, 0.01f, 0.001f, 0.2f, 0.f, 0.f, -2.5f, 0.5f, 0.f, 0.f};
    const float hi[12] = {6.f, 1000.f, 0.9f, 0.5f, 0.2f, 1.f, 10.f, 100.f, 2.5f, 10.f, 0.1f, 0.2f};
    float p[12];
    #pragma unroll
    for (int i = 0; i < 12; ++i)
        p[i] = lo[i] + params[(g*12 + i)*16 + m] * (hi[i] - lo[i]);
    const float pBETA=p[0], pFC=p[1], pK0=p[2], pK1=p[3], pK2=p[4], pLP=p[5],
                pPERC=p[6], pUZL=p[7], pTT=p[8], pCFMAX=p[9], pCFR=p[10], pCWH=p[11];
    const float invFC   = 1.f / pFC;
    const float invLPFC = 1.f / (pLP * pFC);
    const float refCoef = pCFR * pCFMAX;

    // ---- routing weights ----
    const float ta = rtwts[g*2+0] * 2.9f;
    const float tb = rtwts[g*2+1] * 6.5f;
    const float aa = fmaxf(ta, 0.f) + 0.1f;
    const float th = fmaxf(tb, 0.f) + 0.5f;
    float w[LENF];
    const float c0 = expf(-lgammaf(aa)) * powf(th, -aa);
    float wsum = 0.f;
    #pragma unroll
    for (int k = 0; k < LENF; ++k) {
        const float tt = (float)k + 0.5f;
        w[k] = c0 * powf(tt, aa - 1.f) * expf(-tt / th);
        wsum += w[k];
    }
    const float winv = 1.f / wsum;
    #pragma unroll
    for (int k = 0; k < LENF; ++k) w[k] *= winv;

    // ---- chunked LDS staging of x ----
    float stg[NLOAD];
    auto stage_load = [&](int c) {
        const int base = c*CHUNK*4500 + G3;        // x index: t*4500 + g*3 + ch
        #pragma unroll
        for (int k = 0; k < NLOAD; ++k) {
            const int idx = lane + 64*k;           // linear (row*12 + col)
            if (idx < CHUNKDW) {
                const int row = idx / 12, col = idx - row*12;
                stg[k] = x[base + row*4500 + col];
            } else {
                stg[k] = 0.f;
            }
        }
    };
    auto stage_write = [&](int b) {
        #pragma unroll
        for (int k = 0; k < NLOAD; ++k) {
            const int idx = lane + 64*k;
            if (idx < CHUNKDW) lds[b*LDSPAD + idx] = stg[k];
        }
    };

    stage_load(0);
    stage_write(0);

    float h[LENF-1];
    #pragma unroll
    for (int k = 0; k < LENF-1; ++k) h[k] = 0.f;

    float SNOWPACK=0.001f, MELTWATER=0.001f, SM=0.001f, SUZ=0.001f, SLZ=0.001f;
    const float inv16 = 1.f/16.f;

    float* optr = out + g*5 + m;                   // advances 7500 floats per step

    for (int c = 0; c < NCHUNK; ++c) {
        if (c+1 < NCHUNK) stage_load(c+1);         // HBM latency hides under 146 steps
        const float* buf = &lds[(c&1)*LDSPAD + gl*3];

        // software-pipeline LDS reads one step ahead (pure lgkm, tiny, broadcast)
        float Pa = buf[0], Ta = buf[1], Ea = buf[2];

        #pragma unroll 2
        for (int s = 0; s < CHUNK; ++s) {
            const float* nb = buf + (s+1)*ROWDW;   // s=145 reads slack row: dead value
            const float Pn_ = nb[0], Tn_ = nb[1], En_ = nb[2];

            const float Pm = Pa, Tm = Ta, Em = Ea;
            const float is_rain = (Tm >= pTT) ? 1.f : 0.f;
            const float RAIN = Pm * is_rain;
            const float SNOW = Pm - RAIN;
            const float meltcap = fmaxf(pCFMAX*(Tm - pTT), 0.f);
            const float refcap  = fmaxf(refCoef*(pTT - Tm), 0.f);

            SNOWPACK += SNOW;
            const float melt = fminf(meltcap, SNOWPACK);
            MELTWATER += melt;
            SNOWPACK -= melt;
            const float refreeze = fminf(refcap, MELTWATER);
            SNOWPACK += refreeze;
            MELTWATER -= refreeze;
            const float tosoil = fmaxf(MELTWATER - pCWH*SNOWPACK, 0.f);
            MELTWATER -= tosoil;
            float sw = __powf(SM * invFC, pBETA);
            sw = fminf(fmaxf(sw, 0.f), 1.f);
            const float recharge = (RAIN + tosoil) * sw;
            SM = SM + RAIN + tosoil - recharge;
            const float excess = fmaxf(SM - pFC, 0.f);
            SM -= excess;
            const float evap = fminf(fmaxf(SM * invLPFC, 0.f), 1.f);
            const float ETact = fminf(SM, Em * evap);
            SM = fmaxf(SM - ETact, PRECS);
            SUZ += recharge + excess;
            const float PERC = fminf(SUZ, pPERC);
            SUZ -= PERC;
            const float Q0 = pK0 * fmaxf(SUZ - pUZL, 0.f);
            SUZ -= Q0;
            const float Q1 = pK1 * SUZ;
            SUZ -= Q1;
            SLZ += PERC;
            const float Q2 = pK2 * SLZ;
            SLZ -= Q2;

            // 16-lane means, pure VALU (DPP) — result on all lanes
            const float r0 = row16_sum(Q0);
            const float r1 = row16_sum(Q1);
            const float r2 = row16_sum(Q2);
            const float re = row16_sum(ETact);
            const float rq = (r0 + r1 + r2) * inv16;

            // 15-tap routing convolution (registers, compile-time indices)
            float Qs = w[0] * rq;
            #pragma unroll
            for (int k = 1; k < LENF; ++k) Qs += w[k] * h[k-1];
            #pragma unroll
            for (int k = LENF-2; k >= 1; --k) h[k] = h[k-1];
            h[0] = rq;

            // one coalesced store: lane m<5 writes channel m (80B contiguous/block)
            float val = Qs;
            val = (m == 1) ? r0*inv16 : val;
            val = (m == 2) ? r1*inv16 : val;
            val = (m == 3) ? r2*inv16 : val;
            val = (m == 4) ? re*inv16 : val;
            if (m < 5) *optr = val;
            optr += 7500;

            Pa = Pn_; Ta = Tn_; Ea = En_;
        }

        if (c+1 < NCHUNK) stage_write((c+1)&1);    // single-wave block: no barrier
    }
}

extern "C" void kernel_launch(void* const* d_in, const int* in_sizes, int n_in,
                              void* d_out, int out_size, void* d_ws, size_t ws_size,
                              hipStream_t stream)
{
    const float* x      = (const float*)d_in[0];
    const float* params = (const float*)d_in[1];
    const float* rt     = (const float*)d_in[2];
    float* out = (float*)d_out;

    dim3 grid(NGRID / 4), block(64);
    hipLaunchKernelGGL(hbv_scan_kernel, grid, block, 0, stream, x, params, rt, out);
}

// Round 5
// 420.992 us; speedup vs baseline: 1.4701x; 1.0452x over previous
//
#include <hip/hip_runtime.h>
#include <math.h>

#define NSTEP  730
#define NGRID  1500
#define LENF   15
#define PRECS  1e-5f
#define UN     10                 // 730 = 73 * 10
#define XDW    (NSTEP*12)         // 8760 dwords of x per block (4 grids * 3 ch)
#define RQL    (LENF-1+NSTEP)     // 744: conv history pad + 730 steps

// 16-lane sum via DPP xor-butterfly — pure VALU, result on all 16 lanes.
template<int CTRL>
__device__ __forceinline__ float dpp_add(float v) {
    int t = __builtin_amdgcn_update_dpp(0, __float_as_int(v), CTRL, 0xF, 0xF, true);
    return v + __int_as_float(t);
}
__device__ __forceinline__ float row16_sum(float v) {
    v = dpp_add<0xB1>(v);    // quad_perm [1,0,3,2]
    v = dpp_add<0x4E>(v);    // quad_perm [2,3,0,1]
    v = dpp_add<0x141>(v);   // row_half_mirror
    v = dpp_add<0x140>(v);   // row_mirror
    return v;
}

// One thread per (grid,mu); 64-thread block = 1 wave = 4 grids; 375 blocks.
// Phase 1: stage all x into LDS. Phase 2: 730-step scan, per-step work is
// chain + DPP-reduce + tiny stores; rq goes to an LDS ring. Phase 3: all 730
// routing convolutions done lane-parallel from the LDS ring.
__global__ __launch_bounds__(64, 1)
void hbv_scan_kernel(const float* __restrict__ x,       // (730,1500,3)
                     const float* __restrict__ params,  // (1500,12,16)
                     const float* __restrict__ rtwts,   // (1500,2)
                     float* __restrict__ out)           // (730,1500,5)
{
    __shared__ float xs[XDW];          // 35040 B
    __shared__ float rqbuf[4*RQL];     // 11904 B  (total 46.9 KB < 64 KB)

    const int lane = threadIdx.x;
    const int gl   = lane >> 4;
    const int m    = lane & 15;
    const int g    = blockIdx.x*4 + gl;
    const int G3   = blockIdx.x*12;

    // zero the 14-entry conv-history pad of each grid slot
    if (lane < 4*(LENF-1)) {
        const int q = lane / (LENF-1), r = lane - q*(LENF-1);
        rqbuf[q*RQL + r] = 0.f;
    }

    // ---- Phase 1: stage all 730 steps (block's 12 columns) into LDS ----
    for (int base = 0; base < XDW; base += 1024) {
        float tmp[16];
        #pragma unroll
        for (int j = 0; j < 16; ++j) {
            const int idx = base + j*64 + lane;
            const int row = idx / 12, col = idx - row*12;
            tmp[j] = (idx < XDW) ? x[row*4500 + G3 + col] : 0.f;
        }
        #pragma unroll
        for (int j = 0; j < 16; ++j) {
            const int idx = base + j*64 + lane;
            if (idx < XDW) xs[idx] = tmp[j];
        }
    }
    // single-wave block: LDS ops are in program order, no barrier needed

    // ---- scaled parameters ----
    const float lo[12] = {1.f, 50.f, 0.05f, 0.01f, 0.001f, 0.2f, 0.f, 0.f, -2.5f, 0.5f, 0.f, 0.f};
    const float hi[12] = {6.f, 1000.f, 0.9f, 0.5f, 0.2f, 1.f, 10.f, 100.f, 2.5f, 10.f, 0.1f, 0.2f};
    float p[12];
    #pragma unroll
    for (int i = 0; i < 12; ++i)
        p[i] = lo[i] + params[(g*12 + i)*16 + m] * (hi[i] - lo[i]);
    const float pBETA=p[0], pFC=p[1], pK0=p[2], pK1=p[3], pK2=p[4], pLP=p[5],
                pPERC=p[6], pUZL=p[7], pTT=p[8], pCFMAX=p[9], pCFR=p[10], pCWH=p[11];
    const float invFC   = 1.f / pFC;
    const float invLPFC = 1.f / (pLP * pFC);
    const float refCoef = pCFR * pCFMAX;
    const float inv16   = 1.f/16.f;

    float SNOWPACK=0.001f, MELTWATER=0.001f, SM=0.001f, SUZ=0.001f, SLZ=0.001f;

    // ---- Phase 2: the scan (conv-free, staging-free steady state) ----
    int xsb = gl*3;
    for (int tb = 0; tb < NSTEP/UN; ++tb) {
        float Pv[UN], Tv[UN], Ev[UN];
        #pragma unroll
        for (int u = 0; u < UN; ++u) {
            Pv[u] = xs[xsb + u*12 + 0];
            Tv[u] = xs[xsb + u*12 + 1];
            Ev[u] = xs[xsb + u*12 + 2];
        }

        float q0[UN], q1[UN], q2[UN], et[UN];
        #pragma unroll
        for (int u = 0; u < UN; ++u) {
            const float Pm = Pv[u], Tm = Tv[u], Em = Ev[u];
            const float is_rain = (Tm >= pTT) ? 1.f : 0.f;
            const float RAIN = Pm * is_rain;
            const float SNOW = Pm - RAIN;
            const float meltcap = fmaxf(pCFMAX*(Tm - pTT), 0.f);
            const float refcap  = fmaxf(refCoef*(pTT - Tm), 0.f);

            SNOWPACK += SNOW;
            const float melt = fminf(meltcap, SNOWPACK);
            MELTWATER += melt;
            SNOWPACK -= melt;
            const float refreeze = fminf(refcap, MELTWATER);
            SNOWPACK += refreeze;
            MELTWATER -= refreeze;
            const float tosoil = fmaxf(MELTWATER - pCWH*SNOWPACK, 0.f);
            MELTWATER -= tosoil;
            float sw = __powf(SM * invFC, pBETA);
            sw = fminf(fmaxf(sw, 0.f), 1.f);
            const float recharge = (RAIN + tosoil) * sw;
            SM = SM + RAIN + tosoil - recharge;
            const float excess = fmaxf(SM - pFC, 0.f);
            SM -= excess;
            const float evap = fminf(fmaxf(SM * invLPFC, 0.f), 1.f);
            const float ETact = fminf(SM, Em * evap);
            SM = fmaxf(SM - ETact, PRECS);
            SUZ += recharge + excess;
            const float PERC = fminf(SUZ, pPERC);
            SUZ -= PERC;
            const float Q0 = pK0 * fmaxf(SUZ - pUZL, 0.f);
            SUZ -= Q0;
            const float Q1 = pK1 * SUZ;
            SUZ -= Q1;
            SLZ += PERC;
            const float Q2 = pK2 * SLZ;
            SLZ -= Q2;

            q0[u] = Q0; q1[u] = Q1; q2[u] = Q2; et[u] = ETact;
        }

        // DPP reductions (independent across u and across the 4 values)
        #pragma unroll
        for (int u = 0; u < UN; ++u) {
            const float r0 = row16_sum(q0[u]);
            const float r1 = row16_sum(q1[u]);
            const float r2 = row16_sum(q2[u]);
            const float re = row16_sum(et[u]);
            const float rqs = r0 + r1 + r2;          // raw sum; /16 folded into wq
            if (m == 0) rqbuf[gl*RQL + (LENF-1) + tb*UN + u] = rqs;
            float val = re * inv16;
            val = (m == 1) ? r0*inv16 : val;
            val = (m == 2) ? r1*inv16 : val;
            val = (m == 3) ? r2*inv16 : val;
            if (m >= 1 && m <= 4)
                out[(tb*UN + u)*7500 + g*5 + m] = val;
        }

        xsb += 12*UN;
    }

    // ---- Phase 3: routing weights + all 730 convolutions, lane-parallel ----
    const float ta = rtwts[g*2+0] * 2.9f;
    const float tbv = rtwts[g*2+1] * 6.5f;
    const float aa = fmaxf(ta, 0.f) + 0.1f;
    const float th = fmaxf(tbv, 0.f) + 0.5f;
    float wq[LENF];
    const float c0 = expf(-lgammaf(aa)) * powf(th, -aa);
    float wsum = 0.f;
    #pragma unroll
    for (int k = 0; k < LENF; ++k) {
        const float tt = (float)k + 0.5f;
        wq[k] = c0 * powf(tt, aa - 1.f) * expf(-tt / th);
        wsum += wq[k];
    }
    const float wscale = inv16 / wsum;               // fold /16 and normalization
    #pragma unroll
    for (int k = 0; k < LENF; ++k) wq[k] *= wscale;

    const float* rb = &rqbuf[gl*RQL + (LENF-1)];
    for (int i = 0; i < (NSTEP+15)/16; ++i) {
        const int t = m + 16*i;
        if (t < NSTEP) {
            float acc = 0.f;
            #pragma unroll
            for (int k = 0; k < LENF; ++k)
                acc += wq[k] * rb[t - k];            // t-k >= -14 lands in zero pad
            out[t*7500 + g*5] = acc;
        }
    }
}

extern "C" void kernel_launch(void* const* d_in, const int* in_sizes, int n_in,
                              void* d_out, int out_size, void* d_ws, size_t ws_size,
                              hipStream_t stream)
{
    const float* x      = (const float*)d_in[0];
    const float* params = (const float*)d_in[1];
    const float* rt     = (const float*)d_in[2];
    float* out = (float*)d_out;

    dim3 grid(NGRID / 4), block(64);
    hipLaunchKernelGGL(hbv_scan_kernel, grid, block, 0, stream, x, params, rt, out);
}

// Round 6
// 348.344 us; speedup vs baseline: 1.7767x; 1.2086x over previous
//
#include <hip/hip_runtime.h>
#include <math.h>

#define NSTEP  730
#define NGRID  1500
#define LENF   15
#define PRECS  1e-5f
#define CH     32                     // steps per chunk
#define NCHUNK ((NSTEP + CH - 1)/CH)  // 23 (tail = 26)
#define XROW   12                     // dwords per step row (4 grids * 3 ch)
#define XBUFDW (CH*XROW)              // 384
#define QROW   260                    // padded dwords per step slot (256 + 4)
#define RQL    (LENF-1+NSTEP)         // 744

// One thread per (grid,mu); 64-thread block = 1 wave = 4 grids; 375 blocks.
// Scan steady state = state chain + 1 ds_write_b128 (per-lane q-vector).
// All reductions/outputs deferred to a per-chunk lane-parallel epilogue;
// routing conv deferred to a final lane-parallel phase (R5 pattern).
__global__ __launch_bounds__(64, 1)
void hbv_scan_kernel(const float* __restrict__ x,       // (730,1500,3)
                     const float* __restrict__ params,  // (1500,12,16)
                     const float* __restrict__ rtwts,   // (1500,2)
                     float* __restrict__ out)           // (730,1500,5)
{
    __shared__ float xbuf[XBUFDW];        //  1.5 KB
    __shared__ float qbuf[CH*QROW];       // 33.3 KB (s-stride 260: bank-clean)
    __shared__ float rqbuf[4*RQL];        // 11.9 KB

    const int lane = threadIdx.x;
    const int gl   = lane >> 4;
    const int m    = lane & 15;
    const int g    = blockIdx.x*4 + gl;
    const int G3   = blockIdx.x*12;

    // zero the 14-entry conv-history pad of each grid slot
    if (lane < 4*(LENF-1)) {
        const int q = lane / (LENF-1), r = lane - q*(LENF-1);
        rqbuf[q*RQL + r] = 0.f;
    }

    // ---- scaled parameters ----
    const float lo[12] = {1.f, 50.f, 0.05f, 0.01f, 0.001f, 0.2f, 0.f, 0.f, -2.5f, 0.5f, 0.f, 0.f};
    const float hi[12] = {6.f, 1000.f, 0.9f, 0.5f, 0.2f, 1.f, 10.f, 100.f, 2.5f, 10.f, 0.1f, 0.2f};
    float p[12];
    #pragma unroll
    for (int i = 0; i < 12; ++i)
        p[i] = lo[i] + params[(g*12 + i)*16 + m] * (hi[i] - lo[i]);
    const float pBETA=p[0], pFC=p[1], pK0=p[2], pK1=p[3], pK2=p[4], pLP=p[5],
                pPERC=p[6], pUZL=p[7], pTT=p[8], pCFMAX=p[9], pCFR=p[10], pCWH=p[11];
    const float invFC   = 1.f / pFC;
    const float invLPFC = 1.f / (pLP * pFC);
    const float refCoef = pCFR * pCFMAX;
    const float negCMTT = -pCFMAX * pTT;   // meltcap = max(fma(CFMAX,T,negCMTT),0)
    const float refCTT  = refCoef * pTT;   // refcap  = max(fma(-refCoef,T,refCTT),0)
    const float inv16   = 1.f/16.f;

    // ---- chunked x prefetch: 384 dwords/chunk -> 6 regs/lane ----
    float stg[6];
    auto issue_loads = [&](int c) {
        const int nrow = (NSTEP - c*CH < CH) ? (NSTEP - c*CH) : CH;
        const int base = c*CH*4500 + G3;
        #pragma unroll
        for (int j = 0; j < 6; ++j) {
            const int idx = lane + 64*j;
            const int row = idx / 12, col = idx - row*12;
            stg[j] = (idx < nrow*12) ? x[base + row*4500 + col] : 0.f;
        }
    };
    issue_loads(0);

    float SNOWPACK=0.001f, MELTWATER=0.001f, SM=0.001f, SUZ=0.001f, SLZ=0.001f;

    for (int c = 0; c < NCHUNK; ++c) {
        const int nstep = (NSTEP - c*CH < CH) ? (NSTEP - c*CH) : CH;

        // commit prefetched x to LDS, then issue next chunk's loads
        #pragma unroll
        for (int j = 0; j < 6; ++j) {
            const int idx = lane + 64*j;
            if (idx < XBUFDW) xbuf[idx] = stg[j];
        }
        if (c+1 < NCHUNK) issue_loads(c+1);

        // ---- scan: chain + one ds_write_b128 per step ----
        auto do_step = [&](int s) {
            const float Pm = xbuf[s*XROW + gl*3 + 0];
            const float Tm = xbuf[s*XROW + gl*3 + 1];
            const float Em = xbuf[s*XROW + gl*3 + 2];

            const float RAIN    = (Tm >= pTT) ? Pm : 0.f;
            const float SNOW    = Pm - RAIN;
            const float meltcap = fmaxf(fmaf(pCFMAX, Tm, negCMTT), 0.f);
            const float refcap  = fmaxf(fmaf(-refCoef, Tm, refCTT), 0.f);

            SNOWPACK += SNOW;
            const float melt = fminf(meltcap, SNOWPACK);
            MELTWATER += melt;
            SNOWPACK -= melt;
            const float refreeze = fminf(refcap, MELTWATER);
            SNOWPACK += refreeze;
            MELTWATER -= refreeze;
            const float tosoil = fmaxf(fmaf(-pCWH, SNOWPACK, MELTWATER), 0.f);
            MELTWATER -= tosoil;
            const float sw = fminf(__powf(SM * invFC, pBETA), 1.f);  // SM<=FC => >=0
            const float rt = RAIN + tosoil;
            const float recharge = rt * sw;
            SM = SM + rt - recharge;
            const float excess = fmaxf(SM - pFC, 0.f);
            SM -= excess;
            const float evap = fminf(SM * invLPFC, 1.f);             // SM>0 => >=0
            const float ETact = fminf(SM, Em * evap);
            SM = fmaxf(SM - ETact, PRECS);
            SUZ += recharge + excess;
            const float PERC = fminf(SUZ, pPERC);
            SUZ -= PERC;
            const float Q0 = pK0 * fmaxf(SUZ - pUZL, 0.f);
            SUZ -= Q0;
            const float Q1 = pK1 * SUZ;
            SUZ -= Q1;
            SLZ += PERC;
            const float Q2 = pK2 * SLZ;
            SLZ -= Q2;

            float4 qv; qv.x = Q0; qv.y = Q1; qv.z = Q2; qv.w = ETact;
            *(float4*)&qbuf[s*QROW + (gl*16 + m)*4] = qv;   // 16B-aligned
        };
        if (nstep == CH) {
            #pragma unroll 8
            for (int s = 0; s < CH; ++s) do_step(s);
        } else {
            for (int s = 0; s < nstep; ++s) do_step(s);
        }

        // ---- epilogue: lane (gl,m) reduces tasks (gl, s=m) and (gl, s=m+16) ----
        #pragma unroll
        for (int k = 0; k < 2; ++k) {
            const int s = m + 16*k;
            if (s < nstep) {
                float a0=0.f, a1=0.f, a2=0.f, a3=0.f;
                #pragma unroll
                for (int i = 0; i < 16; ++i) {
                    const float4 v = *(const float4*)&qbuf[s*QROW + gl*64 + i*4];
                    a0 += v.x; a1 += v.y; a2 += v.z; a3 += v.w;
                }
                const int t = c*CH + s;
                rqbuf[gl*RQL + (LENF-1) + t] = a0 + a1 + a2;   // /16 folded into wq
                float* ob = out + t*7500 + g*5;
                ob[1] = a0 * inv16;
                ob[2] = a1 * inv16;
                ob[3] = a2 * inv16;
                ob[4] = a3 * inv16;
            }
        }
    }

    // ---- final phase: routing weights + all 730 convolutions, lane-parallel ----
    const float ta  = rtwts[g*2+0] * 2.9f;
    const float tbv = rtwts[g*2+1] * 6.5f;
    const float aa = fmaxf(ta, 0.f) + 0.1f;
    const float th = fmaxf(tbv, 0.f) + 0.5f;
    float wq[LENF];
    const float c0 = expf(-lgammaf(aa)) * powf(th, -aa);
    float wsum = 0.f;
    #pragma unroll
    for (int k = 0; k < LENF; ++k) {
        const float tt = (float)k + 0.5f;
        wq[k] = c0 * powf(tt, aa - 1.f) * expf(-tt / th);
        wsum += wq[k];
    }
    const float wscale = inv16 / wsum;
    #pragma unroll
    for (int k = 0; k < LENF; ++k) wq[k] *= wscale;

    const float* rb = &rqbuf[gl*RQL + (LENF-1)];
    for (int i = 0; i < (NSTEP+15)/16; ++i) {
        const int t = m + 16*i;
        if (t < NSTEP) {
            float acc = 0.f;
            #pragma unroll
            for (int k = 0; k < LENF; ++k)
                acc += wq[k] * rb[t - k];           // t-k >= -14 lands in zero pad
            out[t*7500 + g*5] = acc;
        }
    }
}

extern "C" void kernel_launch(void* const* d_in, const int* in_sizes, int n_in,
                              void* d_out, int out_size, void* d_ws, size_t ws_size,
                              hipStream_t stream)
{
    const float* x      = (const float*)d_in[0];
    const float* params = (const float*)d_in[1];
    const float* rt     = (const float*)d_in[2];
    float* out = (float*)d_out;

    dim3 grid(NGRID / 4), block(64);
    hipLaunchKernelGGL(hbv_scan_kernel, grid, block, 0, stream, x, params, rt, out);
}